// Round 1
// baseline (606.787 us; speedup 1.0000x reference)
//
#include <hip/hip_runtime.h>

#define NB 16
#define NA 98304
#define NM 32
#define NS 32
#define CAP 16384
#define TARGET 2048

typedef unsigned int u32;
typedef unsigned char u8;

struct WS {
  float iou_max[NB * NA];
  u8    iou_arg[NB * NA];
  u32   img_max[NB];
  int   n_pos[NB];
  int   n_neg[NB];
  int   pos_cnt[NB];
  int   neg_cnt[NB];
  u32   keys[NB][4];
  float pos_val[NB * CAP];
  int   pos_idx[NB * CAP];
  float neg_val[NB * CAP];
  int   neg_idx[NB * CAP];
  float cls_img[NB];
  float reg_img[NB];
};

__device__ __forceinline__ u32 rotl32(u32 v, int d) { return (v << d) | (v >> (32 - d)); }

// Threefry-2x32, 20 rounds, exactly as jax/_src/prng.py
__device__ __forceinline__ void threefry2x32(u32 k0, u32 k1, u32 x0, u32 x1, u32& o0, u32& o1) {
  u32 k2 = k0 ^ k1 ^ 0x1BD11BDAu;
  x0 += k0; x1 += k1;
  x0 += x1; x1 = rotl32(x1, 13); x1 ^= x0;
  x0 += x1; x1 = rotl32(x1, 15); x1 ^= x0;
  x0 += x1; x1 = rotl32(x1, 26); x1 ^= x0;
  x0 += x1; x1 = rotl32(x1, 6);  x1 ^= x0;
  x0 += k1; x1 += k2 + 1u;
  x0 += x1; x1 = rotl32(x1, 17); x1 ^= x0;
  x0 += x1; x1 = rotl32(x1, 29); x1 ^= x0;
  x0 += x1; x1 = rotl32(x1, 16); x1 ^= x0;
  x0 += x1; x1 = rotl32(x1, 24); x1 ^= x0;
  x0 += k2; x1 += k0 + 2u;
  x0 += x1; x1 = rotl32(x1, 13); x1 ^= x0;
  x0 += x1; x1 = rotl32(x1, 15); x1 ^= x0;
  x0 += x1; x1 = rotl32(x1, 26); x1 ^= x0;
  x0 += x1; x1 = rotl32(x1, 6);  x1 ^= x0;
  x0 += k0; x1 += k1 + 3u;
  x0 += x1; x1 = rotl32(x1, 17); x1 ^= x0;
  x0 += x1; x1 = rotl32(x1, 29); x1 ^= x0;
  x0 += x1; x1 = rotl32(x1, 16); x1 ^= x0;
  x0 += x1; x1 = rotl32(x1, 24); x1 ^= x0;
  x0 += k1; x1 += k2 + 4u;
  x0 += x1; x1 = rotl32(x1, 13); x1 ^= x0;
  x0 += x1; x1 = rotl32(x1, 15); x1 ^= x0;
  x0 += x1; x1 = rotl32(x1, 26); x1 ^= x0;
  x0 += x1; x1 = rotl32(x1, 6);  x1 ^= x0;
  x0 += k2; x1 += k0 + 5u;
  o0 = x0; o1 = x1;
}

// partitionable random_bits(32) -> uniform(0.1, 1.0), bit-matching jax _uniform
__device__ __forceinline__ float tf_uniform(u32 k0, u32 k1, u32 idx) {
  u32 o0, o1;
  threefry2x32(k0, k1, 0u, idx, o0, o1);
  u32 bits = o0 ^ o1;
  float f = __uint_as_float((bits >> 9) | 0x3F800000u) - 1.0f;  // [0,1)
  float u = __fadd_rn(__fmul_rn(f, (1.0f - 0.1f)), 0.1f);
  return fmaxf(0.1f, u);
}

__global__ __launch_bounds__(64) void k_init(WS* ws) {
  int t = threadIdx.x;
  if (t < NB) {
    ws->img_max[t] = 0u;
    ws->n_pos[t] = 0; ws->n_neg[t] = 0;
    ws->pos_cnt[t] = 0; ws->neg_cnt[t] = 0;
    u32 o0, o1;
    threefry2x32(0u, 42u, 0u, (u32)(2 * t), o0, o1);      // keys[j][0] = split-key 2j
    ws->keys[t][0] = o0; ws->keys[t][1] = o1;
    threefry2x32(0u, 42u, 0u, (u32)(2 * t + 1), o0, o1);  // keys[j][1] = split-key 2j+1
    ws->keys[t][2] = o0; ws->keys[t][3] = o1;
  }
}

__global__ __launch_bounds__(256) void k_iou(const float* __restrict__ anchors,
                                             const float* __restrict__ ann, WS* ws) {
  int b = blockIdx.y;
  int a = blockIdx.x * 256 + threadIdx.x;
  __shared__ float bx1[NM], by1[NM], bx2[NM], by2[NM], barea[NM];
  if (threadIdx.x < NM) {
    int m = threadIdx.x;
    const float* p = ann + ((size_t)b * NM + m) * 5;
    float x1 = fminf(fmaxf(p[0], 0.0f), 512.0f);
    float y1 = fminf(fmaxf(p[1], 0.0f), 512.0f);
    float x2 = fminf(fmaxf(p[2], 0.0f), 512.0f);
    float y2 = fminf(fmaxf(p[3], 0.0f), 512.0f);
    bx1[m] = x1; by1[m] = y1; bx2[m] = x2; by2[m] = y2;
    barea[m] = __fmul_rn(__fsub_rn(x2, x1), __fsub_rn(y2, y1));
  }
  __syncthreads();
  if (a >= NA) return;
  const float* ap = anchors + (size_t)a * 4;
  float ax1 = ap[0], ay1 = ap[1], ax2 = ap[2], ay2 = ap[3];
  float aarea = __fmul_rn(__fsub_rn(ax2, ax1), __fsub_rn(ay2, ay1));
  float best = -1.0f; int bestm = 0;
  for (int m = 0; m < NM; m++) {
    float iw = fmaxf(__fsub_rn(fminf(ax2, bx2[m]), fmaxf(ax1, bx1[m])), 0.0f);
    float ih = fmaxf(__fsub_rn(fminf(ay2, by2[m]), fmaxf(ay1, by1[m])), 0.0f);
    float inter = __fmul_rn(iw, ih);
    float ua = fmaxf(__fsub_rn(__fadd_rn(aarea, barea[m]), inter), 1e-8f);
    float iou = __fdiv_rn(inter, ua);
    if (iou > best) { best = iou; bestm = m; }
  }
  size_t o = (size_t)b * NA + a;
  ws->iou_max[o] = best;
  ws->iou_arg[o] = (u8)bestm;
  __shared__ float red[256];
  red[threadIdx.x] = best;
  __syncthreads();
  for (int s = 128; s > 0; s >>= 1) {
    if (threadIdx.x < s) red[threadIdx.x] = fmaxf(red[threadIdx.x], red[threadIdx.x + s]);
    __syncthreads();
  }
  if (threadIdx.x == 0) atomicMax(&ws->img_max[b], __float_as_uint(red[0]));
}

__global__ __launch_bounds__(256) void k_count(WS* ws) {
  int b = blockIdx.y;
  int a = blockIdx.x * 256 + threadIdx.x;
  __shared__ int cp, cn;
  if (threadIdx.x == 0) { cp = 0; cn = 0; }
  __syncthreads();
  if (a < NA) {
    float im = ws->iou_max[(size_t)b * NA + a];
    float thresh = fminf(__uint_as_float(ws->img_max[b]), 0.7f);
    if (im >= thresh) atomicAdd(&cp, 1);
    if (im < 0.4f && im >= 0.1f) atomicAdd(&cn, 1);
  }
  __syncthreads();
  if (threadIdx.x == 0) {
    if (cp) atomicAdd(&ws->n_pos[b], cp);
    if (cn) atomicAdd(&ws->n_neg[b], cn);
  }
}

__global__ __launch_bounds__(256) void k_push(WS* ws) {
  int b = blockIdx.y;
  int a = blockIdx.x * 256 + threadIdx.x;
  if (a >= NA) return;
  float im = ws->iou_max[(size_t)b * NA + a];
  float thresh = fminf(__uint_as_float(ws->img_max[b]), 0.7f);
  bool isp = (im >= thresh);
  bool isn = (im < 0.4f) && (im >= 0.1f);
  if (!isp && !isn) return;
  if (isp) {
    float u = tf_uniform(ws->keys[b][0], ws->keys[b][1], (u32)a);
    int n = ws->n_pos[b];
    float cut = (n <= TARGET) ? -1.0f : (1.0f - 0.9f * ((float)TARGET / (float)n));
    if (u >= cut) {
      int p = atomicAdd(&ws->pos_cnt[b], 1);
      if (p < CAP) { ws->pos_val[b * CAP + p] = u; ws->pos_idx[b * CAP + p] = a; }
    }
  }
  if (isn) {
    float u = tf_uniform(ws->keys[b][2], ws->keys[b][3], (u32)a);
    int n = ws->n_neg[b];
    float cut = (n <= TARGET) ? -1.0f : (1.0f - 0.9f * ((float)TARGET / (float)n));
    if (u >= cut) {
      int p = atomicAdd(&ws->neg_cnt[b], 1);
      if (p < CAP) { ws->neg_val[b * CAP + p] = u; ws->neg_idx[b * CAP + p] = a; }
    }
  }
}

__global__ __launch_bounds__(256) void k_select(const float* __restrict__ cls,
                                                const float* __restrict__ reg,
                                                const float* __restrict__ anchors,
                                                const float* __restrict__ ann,
                                                const float* __restrict__ w, WS* ws) {
  int b = blockIdx.x;
  int tid = threadIdx.x;
  __shared__ float sv[256];
  __shared__ int sa[256];
  __shared__ int sp[256];
  __shared__ int selp[NS];
  __shared__ int seln[2 * NS];
  __shared__ float tpos[NS], treg[NS], tneg[2 * NS];

  int n_pos = ws->n_pos[b];
  int n_neg = ws->n_neg[b];
  int mp = min(ws->pos_cnt[b], CAP);
  int mn = min(ws->neg_cnt[b], CAP);
  int K = min(NS, n_pos);
  int rp = min(K, mp);
  int rn = min(min(2 * NS - K, n_neg), mn);

  // top-rp positives by (value desc, index asc) — lax.top_k tie-break
  {
    float* pv = ws->pos_val + b * CAP;
    int* pi = ws->pos_idx + b * CAP;
    for (int r = 0; r < rp; r++) {
      float bv = -1e30f; int ba = 0x7FFFFFFF; int bp = -1;
      for (int i = tid; i < mp; i += 256) {
        float v = pv[i]; int aa = pi[i];
        if (v > bv || (v == bv && aa < ba)) { bv = v; ba = aa; bp = i; }
      }
      sv[tid] = bv; sa[tid] = ba; sp[tid] = bp;
      __syncthreads();
      for (int s = 128; s > 0; s >>= 1) {
        if (tid < s) {
          if (sv[tid + s] > sv[tid] || (sv[tid + s] == sv[tid] && sa[tid + s] < sa[tid])) {
            sv[tid] = sv[tid + s]; sa[tid] = sa[tid + s]; sp[tid] = sp[tid + s];
          }
        }
        __syncthreads();
      }
      if (tid == 0) { selp[r] = sa[0]; if (sp[0] >= 0) pv[sp[0]] = -2.0f; }
      __syncthreads();
    }
  }
  // top-rn negatives
  {
    float* nv = ws->neg_val + b * CAP;
    int* ni = ws->neg_idx + b * CAP;
    for (int r = 0; r < rn; r++) {
      float bv = -1e30f; int ba = 0x7FFFFFFF; int bp = -1;
      for (int i = tid; i < mn; i += 256) {
        float v = nv[i]; int aa = ni[i];
        if (v > bv || (v == bv && aa < ba)) { bv = v; ba = aa; bp = i; }
      }
      sv[tid] = bv; sa[tid] = ba; sp[tid] = bp;
      __syncthreads();
      for (int s = 128; s > 0; s >>= 1) {
        if (tid < s) {
          if (sv[tid + s] > sv[tid] || (sv[tid + s] == sv[tid] && sa[tid + s] < sa[tid])) {
            sv[tid] = sv[tid + s]; sa[tid] = sa[tid + s]; sp[tid] = sp[tid + s];
          }
        }
        __syncthreads();
      }
      if (tid == 0) { seln[r] = sa[0]; if (sp[0] >= 0) nv[sp[0]] = -2.0f; }
      __syncthreads();
    }
  }

  if (tid < NS) { tpos[tid] = 0.0f; treg[tid] = 0.0f; }
  if (tid < 2 * NS) tneg[tid] = 0.0f;
  __syncthreads();

  const float PLO = 1e-7f;
  const float PHI = (float)(1.0 - 1e-7);
  if (tid < rp) {
    int a = selp[tid];
    float p = cls[((size_t)b * NA + a) * 2 + 0];
    p = fminf(fmaxf(p, PLO), PHI);
    tpos[tid] = -logf(p);
    // regression smooth-L1 on this positive
    const float* apt = anchors + (size_t)a * 4;
    float ax1 = apt[0], ay1 = apt[1], ax2 = apt[2], ay2 = apt[3];
    float aw_ = __fsub_rn(ax2, ax1), ah_ = __fsub_rn(ay2, ay1);
    float acx = __fadd_rn(ax1, __fmul_rn(0.5f, aw_));
    float acy = __fadd_rn(ay1, __fmul_rn(0.5f, ah_));
    int m = ws->iou_arg[(size_t)b * NA + a];
    const float* g = ann + ((size_t)b * NM + m) * 5;
    float gx1 = fminf(fmaxf(g[0], 0.0f), 512.0f);
    float gy1 = fminf(fmaxf(g[1], 0.0f), 512.0f);
    float gx2 = fminf(fmaxf(g[2], 0.0f), 512.0f);
    float gy2 = fminf(fmaxf(g[3], 0.0f), 512.0f);
    float gw = __fsub_rn(gx2, gx1), gh = __fsub_rn(gy2, gy1);
    float gcx = __fadd_rn(gx1, __fmul_rn(0.5f, gw));
    float gcy = __fadd_rn(gy1, __fmul_rn(0.5f, gh));
    gw = fmaxf(gw, 1.0f); gh = fmaxf(gh, 1.0f);
    float t0 = __fdiv_rn(__fdiv_rn(__fsub_rn(gcx, acx), aw_), 0.1f);
    float t1 = __fdiv_rn(__fdiv_rn(__fsub_rn(gcy, acy), ah_), 0.1f);
    float t2 = __fdiv_rn(logf(__fdiv_rn(gw, aw_)), 0.2f);
    float t3 = __fdiv_rn(logf(__fdiv_rn(gh, ah_)), 0.2f);
    const float* rg = reg + ((size_t)b * NA + a) * 4;
    float tt[4] = {t0, t1, t2, t3};
    float s = 0.0f;
    for (int c = 0; c < 4; c++) {
      float d = fabsf(__fsub_rn(tt[c], rg[c]));
      float q = (d <= (float)(1.0 / 9.0)) ? __fmul_rn(__fmul_rn(4.5f, d), d)
                                          : __fsub_rn(d, (float)(0.5 / 9.0));
      s = __fadd_rn(s, q);
    }
    treg[tid] = s;
  }
  if (tid < rn) {
    int a = seln[tid];
    bool ispos = false;
    for (int i = 0; i < rp; i++) if (selp[i] == a) ispos = true;
    if (!ispos) {  // pos target overrides: that slot contributes nothing extra
      float p = cls[((size_t)b * NA + a) * 2 + 1];
      p = fminf(fmaxf(p, PLO), PHI);
      tneg[tid] = -logf(p);
    }
  }
  __syncthreads();
  if (tid == 0) {
    float cs = 0.0f;
    for (int i = 0; i < NS; i++) cs = __fadd_rn(cs, tpos[i]);
    for (int i = 0; i < 2 * NS; i++) cs = __fadd_rn(cs, tneg[i]);
    float rs = 0.0f;
    for (int i = 0; i < NS; i++) rs = __fadd_rn(rs, treg[i]);
    ws->cls_img[b] = __fdiv_rn(cs, 64.0f);
    ws->reg_img[b] = __fdiv_rn(__fmul_rn(rs, w[b * 4 + 0]), 64.0f);
  }
}

__global__ __launch_bounds__(64) void k_final(WS* ws, float* out) {
  if (threadIdx.x == 0) {
    float c = 0.0f, r = 0.0f;
    for (int b = 0; b < NB; b++) { c = __fadd_rn(c, ws->cls_img[b]); r = __fadd_rn(r, ws->reg_img[b]); }
    out[0] = __fdiv_rn(c, 16.0f);
    out[1] = __fdiv_rn(r, 16.0f);
  }
}

extern "C" void kernel_launch(void* const* d_in, const int* in_sizes, int n_in,
                              void* d_out, int out_size, void* d_ws, size_t ws_size,
                              hipStream_t stream) {
  const float* cls = (const float*)d_in[0];
  const float* reg = (const float*)d_in[1];
  const float* anchors = (const float*)d_in[2];  // (1, A, 4) -> anchors[0]
  const float* ann = (const float*)d_in[3];      // (B, M, 5)
  const float* w = (const float*)d_in[4];        // (B, 4)
  float* out = (float*)d_out;
  if (ws_size < sizeof(WS)) return;  // need ~12 MB scratch
  WS* ws = (WS*)d_ws;

  hipLaunchKernelGGL(k_init, dim3(1), dim3(64), 0, stream, ws);
  hipLaunchKernelGGL(k_iou, dim3(NA / 256, NB), dim3(256), 0, stream, anchors, ann, ws);
  hipLaunchKernelGGL(k_count, dim3(NA / 256, NB), dim3(256), 0, stream, ws);
  hipLaunchKernelGGL(k_push, dim3(NA / 256, NB), dim3(256), 0, stream, ws);
  hipLaunchKernelGGL(k_select, dim3(NB), dim3(256), 0, stream, cls, reg, anchors, ann, w, ws);
  hipLaunchKernelGGL(k_final, dim3(1), dim3(64), 0, stream, ws, out);
}

// Round 2
// 132.769 us; speedup vs baseline: 4.5703x; 4.5703x over previous
//
#include <hip/hip_runtime.h>

#define NB 16
#define NA 98304
#define NM 32
#define NS 32
#define BLK 24          // blocks per image in k_iou/k_push: 1024 thr x 4 anchors = 4096
#define TARGET 256      // expected kept candidates per list (superset of top-64, ~40 sigma margin)
#define GCAP 1024       // global candidate capacity per image per list
#define BCAP 768        // per-block LDS compaction capacity

typedef unsigned int u32;
typedef unsigned long long u64;

static_assert(NA == BLK * 1024 * 4, "coverage");

struct WS {
  u64   pos_key[NB * GCAP];
  u64   neg_key[NB * GCAP];
  float iou_max[NB * NA];
  u32   iou_arg4[NB * NA / 4];     // 4 x u8 packed
  float blk_max[NB * BLK];
  int   blk_nneg[NB * BLK];
  int   blk_npos[NB * BLK];
  float thresh[NB], cut_pos[NB], cut_neg[NB];
  int   n_neg[NB], n_pos07[NB], ge07[NB];
  u32   keys[NB][4];
  int   pos_cnt[NB], neg_cnt[NB];
  float cls_img[NB], reg_img[NB];
};

__device__ __forceinline__ u32 rotl32(u32 v, int d) { return (v << d) | (v >> (32 - d)); }

// Threefry-2x32, 20 rounds, exactly as jax/_src/prng.py
__device__ __forceinline__ void threefry2x32(u32 k0, u32 k1, u32 x0, u32 x1, u32& o0, u32& o1) {
  u32 k2 = k0 ^ k1 ^ 0x1BD11BDAu;
  x0 += k0; x1 += k1;
  x0 += x1; x1 = rotl32(x1, 13); x1 ^= x0;
  x0 += x1; x1 = rotl32(x1, 15); x1 ^= x0;
  x0 += x1; x1 = rotl32(x1, 26); x1 ^= x0;
  x0 += x1; x1 = rotl32(x1, 6);  x1 ^= x0;
  x0 += k1; x1 += k2 + 1u;
  x0 += x1; x1 = rotl32(x1, 17); x1 ^= x0;
  x0 += x1; x1 = rotl32(x1, 29); x1 ^= x0;
  x0 += x1; x1 = rotl32(x1, 16); x1 ^= x0;
  x0 += x1; x1 = rotl32(x1, 24); x1 ^= x0;
  x0 += k2; x1 += k0 + 2u;
  x0 += x1; x1 = rotl32(x1, 13); x1 ^= x0;
  x0 += x1; x1 = rotl32(x1, 15); x1 ^= x0;
  x0 += x1; x1 = rotl32(x1, 26); x1 ^= x0;
  x0 += x1; x1 = rotl32(x1, 6);  x1 ^= x0;
  x0 += k0; x1 += k1 + 3u;
  x0 += x1; x1 = rotl32(x1, 17); x1 ^= x0;
  x0 += x1; x1 = rotl32(x1, 29); x1 ^= x0;
  x0 += x1; x1 = rotl32(x1, 16); x1 ^= x0;
  x0 += x1; x1 = rotl32(x1, 24); x1 ^= x0;
  x0 += k1; x1 += k2 + 4u;
  x0 += x1; x1 = rotl32(x1, 13); x1 ^= x0;
  x0 += x1; x1 = rotl32(x1, 15); x1 ^= x0;
  x0 += x1; x1 = rotl32(x1, 26); x1 ^= x0;
  x0 += x1; x1 = rotl32(x1, 6);  x1 ^= x0;
  x0 += k2; x1 += k0 + 5u;
  o0 = x0; o1 = x1;
}

// partitionable random_bits(32) -> uniform(0.1, 1.0), bit-matching jax _uniform
__device__ __forceinline__ float tf_uniform(u32 k0, u32 k1, u32 idx) {
  u32 o0, o1;
  threefry2x32(k0, k1, 0u, idx, o0, o1);
  u32 bits = o0 ^ o1;
  float f = __uint_as_float((bits >> 9) | 0x3F800000u) - 1.0f;  // [0,1)
  float u = __fadd_rn(__fmul_rn(f, (1.0f - 0.1f)), 0.1f);
  return fmaxf(0.1f, u);
}

__device__ __forceinline__ u64 pack_key(float u, u32 a) {
  return ((u64)__float_as_uint(u) << 32) | (u64)(u32)(~a);
}

// K1: IoU max/argmax per anchor + per-block stats (no atomics)
__global__ __launch_bounds__(1024) void k_iou(const float* __restrict__ anchors,
                                              const float* __restrict__ ann,
                                              WS* __restrict__ ws) {
  int b = blockIdx.y;
  int tid = threadIdx.x;
  int a0 = (blockIdx.x * 1024 + tid) * 4;
  __shared__ float bx1[NM], by1[NM], bx2[NM], by2[NM], barea[NM];
  __shared__ float wmax[16];
  __shared__ int wneg[16], wpos[16];
  if (tid < NM) {
    int m = tid;
    const float* p = ann + ((size_t)b * NM + m) * 5;
    float x1 = fminf(fmaxf(p[0], 0.0f), 512.0f);
    float y1 = fminf(fmaxf(p[1], 0.0f), 512.0f);
    float x2 = fminf(fmaxf(p[2], 0.0f), 512.0f);
    float y2 = fminf(fmaxf(p[3], 0.0f), 512.0f);
    bx1[m] = x1; by1[m] = y1; bx2[m] = x2; by2[m] = y2;
    barea[m] = __fmul_rn(__fsub_rn(x2, x1), __fsub_rn(y2, y1));
  }
  __syncthreads();

  const float4* a4 = (const float4*)anchors;
  float om[4];
  u32 pack = 0;
  float lmax = -1.0f;
  int cneg = 0, cpos = 0;
  for (int k = 0; k < 4; k++) {
    int a = a0 + k;
    float4 ap = a4[a];
    float aarea = __fmul_rn(__fsub_rn(ap.z, ap.x), __fsub_rn(ap.w, ap.y));
    float best = -1.0f; int bestm = 0;
    for (int m = 0; m < NM; m++) {
      float iw = fmaxf(__fsub_rn(fminf(ap.z, bx2[m]), fmaxf(ap.x, bx1[m])), 0.0f);
      float ih = fmaxf(__fsub_rn(fminf(ap.w, by2[m]), fmaxf(ap.y, by1[m])), 0.0f);
      float inter = __fmul_rn(iw, ih);
      float ua = fmaxf(__fsub_rn(__fadd_rn(aarea, barea[m]), inter), 1e-8f);
      float iou = __fdiv_rn(inter, ua);
      if (iou > best) { best = iou; bestm = m; }
    }
    om[k] = best;
    pack |= ((u32)bestm) << (8 * k);
    lmax = fmaxf(lmax, best);
    cneg += (best < 0.4f && best >= 0.1f) ? 1 : 0;
    cpos += (best >= 0.7f) ? 1 : 0;
  }
  *(float4*)&ws->iou_max[(size_t)b * NA + a0] = make_float4(om[0], om[1], om[2], om[3]);
  ws->iou_arg4[((size_t)b * NA + a0) >> 2] = pack;

  // wave reduce then cross-wave via LDS
  for (int s = 32; s > 0; s >>= 1) {
    lmax = fmaxf(lmax, __shfl_xor(lmax, s));
    cneg += __shfl_xor(cneg, s);
    cpos += __shfl_xor(cpos, s);
  }
  int wid = tid >> 6;
  if ((tid & 63) == 0) { wmax[wid] = lmax; wneg[wid] = cneg; wpos[wid] = cpos; }
  __syncthreads();
  if (tid < 16) {
    lmax = wmax[tid]; cneg = wneg[tid]; cpos = wpos[tid];
    for (int s = 8; s > 0; s >>= 1) {
      lmax = fmaxf(lmax, __shfl_xor(lmax, s));
      cneg += __shfl_xor(cneg, s);
      cpos += __shfl_xor(cpos, s);
    }
    if (tid == 0) {
      int o = b * BLK + blockIdx.x;
      ws->blk_max[o] = lmax;
      ws->blk_nneg[o] = cneg;
      ws->blk_npos[o] = cpos;
    }
  }
}

// K2: per-image reduce of block stats; thresholds, cuts, PRNG keys, zero counters
__global__ __launch_bounds__(64) void k_stats(WS* __restrict__ ws) {
  int b = blockIdx.x, l = threadIdx.x;
  float m = (l < BLK) ? ws->blk_max[b * BLK + l] : -1.0f;
  int nn = (l < BLK) ? ws->blk_nneg[b * BLK + l] : 0;
  int np = (l < BLK) ? ws->blk_npos[b * BLK + l] : 0;
  for (int s = 32; s > 0; s >>= 1) {
    m = fmaxf(m, __shfl_xor(m, s));
    nn += __shfl_xor(nn, s);
    np += __shfl_xor(np, s);
  }
  if (l == 0) {
    ws->thresh[b] = fminf(m, 0.7f);
    int ge = (m >= 0.7f) ? 1 : 0;
    ws->ge07[b] = ge;
    ws->n_neg[b] = nn;
    ws->n_pos07[b] = np;
    ws->cut_neg[b] = (nn <= TARGET) ? -1.0f : (1.0f - 0.9f * ((float)TARGET / (float)nn));
    ws->cut_pos[b] = (ge && np > TARGET) ? (1.0f - 0.9f * ((float)TARGET / (float)np)) : -1.0f;
    ws->pos_cnt[b] = 0;
    ws->neg_cnt[b] = 0;
    u32 o0, o1;
    threefry2x32(0u, 42u, 0u, (u32)(2 * b), o0, o1);
    ws->keys[b][0] = o0; ws->keys[b][1] = o1;
    threefry2x32(0u, 42u, 0u, (u32)(2 * b + 1), o0, o1);
    ws->keys[b][2] = o0; ws->keys[b][3] = o1;
  }
}

// K3: push kept candidates with per-block LDS compaction; 1 global atomic per block per list
__global__ __launch_bounds__(1024) void k_push(WS* __restrict__ ws) {
  int b = blockIdx.y, tid = threadIdx.x;
  int a0 = (blockIdx.x * 1024 + tid) * 4;
  __shared__ u64 pbuf[BCAP], nbuf[BCAP];
  __shared__ int pcnt, ncnt, pbase, nbase;
  if (tid == 0) { pcnt = 0; ncnt = 0; }
  __syncthreads();
  float thresh = ws->thresh[b];
  float cp = ws->cut_pos[b], cn = ws->cut_neg[b];
  u32 k0 = ws->keys[b][0], k1 = ws->keys[b][1];
  u32 k2 = ws->keys[b][2], k3 = ws->keys[b][3];
  float4 im4 = *(const float4*)&ws->iou_max[(size_t)b * NA + a0];
  float imv[4] = {im4.x, im4.y, im4.z, im4.w};
  for (int k = 0; k < 4; k++) {
    float im = imv[k];
    u32 a = (u32)(a0 + k);
    if (im >= thresh) {
      float u = tf_uniform(k0, k1, a);
      if (u >= cp) {
        int p = atomicAdd(&pcnt, 1);
        if (p < BCAP) pbuf[p] = pack_key(u, a);
      }
    }
    if (im < 0.4f && im >= 0.1f) {
      float u = tf_uniform(k2, k3, a);
      if (u >= cn) {
        int p = atomicAdd(&ncnt, 1);
        if (p < BCAP) nbuf[p] = pack_key(u, a);
      }
    }
  }
  __syncthreads();
  if (tid == 0) {
    pbase = (pcnt > 0) ? atomicAdd(&ws->pos_cnt[b], pcnt) : 0;  // unclamped: exact n_pos bookkeeping
    nbase = (ncnt > 0) ? atomicAdd(&ws->neg_cnt[b], ncnt) : 0;
  }
  __syncthreads();
  int pc = min(pcnt, BCAP), nc = min(ncnt, BCAP);
  for (int i = tid; i < pc; i += 1024) { int g = pbase + i; if (g < GCAP) ws->pos_key[b * GCAP + g] = pbuf[i]; }
  for (int i = tid; i < nc; i += 1024) { int g = nbase + i; if (g < GCAP) ws->neg_key[b * GCAP + g] = nbuf[i]; }
}

// K4: one wave per image — iterative u64-argmax selection + loss terms
__global__ __launch_bounds__(64) void k_select(const float* __restrict__ cls,
                                               const float* __restrict__ reg,
                                               const float* __restrict__ anchors,
                                               const float* __restrict__ ann,
                                               const float* __restrict__ w,
                                               WS* __restrict__ ws) {
  int b = blockIdx.x, l = threadIdx.x;
  __shared__ u64 pk[GCAP], nk[GCAP];
  __shared__ int selp[NS], seln[2 * NS];
  __shared__ float tpos[NS], treg[NS], tneg[2 * NS];

  int mp = min(ws->pos_cnt[b], GCAP);
  int mn = min(ws->neg_cnt[b], GCAP);
  int n_pos = ws->ge07[b] ? ws->n_pos07[b] : ws->pos_cnt[b];
  int n_neg = ws->n_neg[b];
  int K = min(NS, n_pos);
  int rp = min(K, mp);
  int rn = min(min(2 * NS - K, n_neg), mn);

  for (int i = l; i < mp; i += 64) pk[i] = ws->pos_key[b * GCAP + i];
  for (int i = l; i < mn; i += 64) nk[i] = ws->neg_key[b * GCAP + i];
  __syncthreads();

  for (int r = 0; r < rp; r++) {
    u64 best = 0;
    for (int i = l; i < mp; i += 64) { u64 v = pk[i]; if (v > best) best = v; }
    for (int s = 32; s > 0; s >>= 1) { u64 o = __shfl_xor(best, s); if (o > best) best = o; }
    if (l == 0) selp[r] = (int)(~(u32)best);
    for (int i = l; i < mp; i += 64) if (pk[i] == best) pk[i] = 0;
    __syncthreads();
  }
  for (int r = 0; r < rn; r++) {
    u64 best = 0;
    for (int i = l; i < mn; i += 64) { u64 v = nk[i]; if (v > best) best = v; }
    for (int s = 32; s > 0; s >>= 1) { u64 o = __shfl_xor(best, s); if (o > best) best = o; }
    if (l == 0) seln[r] = (int)(~(u32)best);
    for (int i = l; i < mn; i += 64) if (nk[i] == best) nk[i] = 0;
    __syncthreads();
  }

  if (l < NS) { tpos[l] = 0.0f; treg[l] = 0.0f; }
  tneg[l] = 0.0f;
  __syncthreads();

  const float PLO = 1e-7f;
  const float PHI = (float)(1.0 - 1e-7);
  if (l < rp) {
    int a = selp[l];
    float p = cls[((size_t)b * NA + a) * 2 + 0];
    p = fminf(fmaxf(p, PLO), PHI);
    tpos[l] = -logf(p);
    float4 apf = ((const float4*)anchors)[a];
    float ax1 = apf.x, ay1 = apf.y, ax2 = apf.z, ay2 = apf.w;
    float aw_ = __fsub_rn(ax2, ax1), ah_ = __fsub_rn(ay2, ay1);
    float acx = __fadd_rn(ax1, __fmul_rn(0.5f, aw_));
    float acy = __fadd_rn(ay1, __fmul_rn(0.5f, ah_));
    int m = (int)((ws->iou_arg4[((size_t)b * NA + a) >> 2] >> (8 * (a & 3))) & 0xFFu);
    const float* g = ann + ((size_t)b * NM + m) * 5;
    float gx1 = fminf(fmaxf(g[0], 0.0f), 512.0f);
    float gy1 = fminf(fmaxf(g[1], 0.0f), 512.0f);
    float gx2 = fminf(fmaxf(g[2], 0.0f), 512.0f);
    float gy2 = fminf(fmaxf(g[3], 0.0f), 512.0f);
    float gw = __fsub_rn(gx2, gx1), gh = __fsub_rn(gy2, gy1);
    float gcx = __fadd_rn(gx1, __fmul_rn(0.5f, gw));
    float gcy = __fadd_rn(gy1, __fmul_rn(0.5f, gh));
    gw = fmaxf(gw, 1.0f); gh = fmaxf(gh, 1.0f);
    float t0 = __fdiv_rn(__fdiv_rn(__fsub_rn(gcx, acx), aw_), 0.1f);
    float t1 = __fdiv_rn(__fdiv_rn(__fsub_rn(gcy, acy), ah_), 0.1f);
    float t2 = __fdiv_rn(logf(__fdiv_rn(gw, aw_)), 0.2f);
    float t3 = __fdiv_rn(logf(__fdiv_rn(gh, ah_)), 0.2f);
    const float* rg = reg + ((size_t)b * NA + a) * 4;
    float tt[4] = {t0, t1, t2, t3};
    float s = 0.0f;
    for (int c = 0; c < 4; c++) {
      float d = fabsf(__fsub_rn(tt[c], rg[c]));
      float q = (d <= (float)(1.0 / 9.0)) ? __fmul_rn(__fmul_rn(4.5f, d), d)
                                          : __fsub_rn(d, (float)(0.5 / 9.0));
      s = __fadd_rn(s, q);
    }
    treg[l] = s;
  }
  if (l < rn) {
    int a = seln[l];
    bool ispos = false;
    for (int i = 0; i < rp; i++) if (selp[i] == a) ispos = true;
    if (!ispos) {
      float p = cls[((size_t)b * NA + a) * 2 + 1];
      p = fminf(fmaxf(p, PLO), PHI);
      tneg[l] = -logf(p);
    }
  }
  __syncthreads();
  if (l == 0) {
    float cs = 0.0f;
    for (int i = 0; i < NS; i++) cs = __fadd_rn(cs, tpos[i]);
    for (int i = 0; i < 2 * NS; i++) cs = __fadd_rn(cs, tneg[i]);
    float rs = 0.0f;
    for (int i = 0; i < NS; i++) rs = __fadd_rn(rs, treg[i]);
    ws->cls_img[b] = __fdiv_rn(cs, 64.0f);
    ws->reg_img[b] = __fdiv_rn(__fmul_rn(rs, w[b * 4 + 0]), 64.0f);
  }
}

__global__ __launch_bounds__(64) void k_final(WS* __restrict__ ws, float* __restrict__ out) {
  if (threadIdx.x == 0) {
    float c = 0.0f, r = 0.0f;
    for (int b = 0; b < NB; b++) {
      c = __fadd_rn(c, ws->cls_img[b]);
      r = __fadd_rn(r, ws->reg_img[b]);
    }
    out[0] = __fdiv_rn(c, 16.0f);
    out[1] = __fdiv_rn(r, 16.0f);
  }
}

extern "C" void kernel_launch(void* const* d_in, const int* in_sizes, int n_in,
                              void* d_out, int out_size, void* d_ws, size_t ws_size,
                              hipStream_t stream) {
  const float* cls = (const float*)d_in[0];
  const float* reg = (const float*)d_in[1];
  const float* anchors = (const float*)d_in[2];  // (1, A, 4)
  const float* ann = (const float*)d_in[3];      // (B, M, 5)
  const float* w = (const float*)d_in[4];        // (B, 4)
  float* out = (float*)d_out;
  if (ws_size < sizeof(WS)) return;
  WS* ws = (WS*)d_ws;

  hipLaunchKernelGGL(k_iou, dim3(BLK, NB), dim3(1024), 0, stream, anchors, ann, ws);
  hipLaunchKernelGGL(k_stats, dim3(NB), dim3(64), 0, stream, ws);
  hipLaunchKernelGGL(k_push, dim3(BLK, NB), dim3(1024), 0, stream, ws);
  hipLaunchKernelGGL(k_select, dim3(NB), dim3(64), 0, stream, cls, reg, anchors, ann, w, ws);
  hipLaunchKernelGGL(k_final, dim3(1), dim3(64), 0, stream, ws, out);
}

// Round 3
// 81.320 us; speedup vs baseline: 7.4617x; 1.6327x over previous
//
#include <hip/hip_runtime.h>

#define NB 16
#define NA 98304
#define NM 32
#define NS 32
#define BLK 24          // blocks per image in k_iou/k_push: 1024 thr x 4 anchors = 4096
#define TARGET 256      // expected kept candidates per list (superset of top-64, ~12 sigma margin)
#define GCAP 1024       // global candidate capacity per image per list
#define BCAP 768        // per-block LDS compaction capacity

typedef unsigned int u32;
typedef unsigned long long u64;

static_assert(NA == BLK * 1024 * 4, "coverage");

struct WS {
  u64   pos_key[NB * GCAP];
  u64   neg_key[NB * GCAP];
  float iou_max[NB * NA];
  u32   iou_arg4[NB * NA / 4];     // 4 x u8 packed
  float blk_max[NB * BLK];
  int   blk_nneg[NB * BLK];
  int   blk_npos[NB * BLK];
  float thresh[NB], cut_pos[NB], cut_neg[NB];
  int   n_neg[NB], n_pos07[NB], ge07[NB];
  u32   keys[NB][4];
  int   pos_cnt[NB], neg_cnt[NB];
  float cls_img[NB], reg_img[NB];
};

__device__ __forceinline__ u32 rotl32(u32 v, int d) { return (v << d) | (v >> (32 - d)); }

// Threefry-2x32, 20 rounds, exactly as jax/_src/prng.py
__device__ __forceinline__ void threefry2x32(u32 k0, u32 k1, u32 x0, u32 x1, u32& o0, u32& o1) {
  u32 k2 = k0 ^ k1 ^ 0x1BD11BDAu;
  x0 += k0; x1 += k1;
  x0 += x1; x1 = rotl32(x1, 13); x1 ^= x0;
  x0 += x1; x1 = rotl32(x1, 15); x1 ^= x0;
  x0 += x1; x1 = rotl32(x1, 26); x1 ^= x0;
  x0 += x1; x1 = rotl32(x1, 6);  x1 ^= x0;
  x0 += k1; x1 += k2 + 1u;
  x0 += x1; x1 = rotl32(x1, 17); x1 ^= x0;
  x0 += x1; x1 = rotl32(x1, 29); x1 ^= x0;
  x0 += x1; x1 = rotl32(x1, 16); x1 ^= x0;
  x0 += x1; x1 = rotl32(x1, 24); x1 ^= x0;
  x0 += k2; x1 += k0 + 2u;
  x0 += x1; x1 = rotl32(x1, 13); x1 ^= x0;
  x0 += x1; x1 = rotl32(x1, 15); x1 ^= x0;
  x0 += x1; x1 = rotl32(x1, 26); x1 ^= x0;
  x0 += x1; x1 = rotl32(x1, 6);  x1 ^= x0;
  x0 += k0; x1 += k1 + 3u;
  x0 += x1; x1 = rotl32(x1, 17); x1 ^= x0;
  x0 += x1; x1 = rotl32(x1, 29); x1 ^= x0;
  x0 += x1; x1 = rotl32(x1, 16); x1 ^= x0;
  x0 += x1; x1 = rotl32(x1, 24); x1 ^= x0;
  x0 += k1; x1 += k2 + 4u;
  x0 += x1; x1 = rotl32(x1, 13); x1 ^= x0;
  x0 += x1; x1 = rotl32(x1, 15); x1 ^= x0;
  x0 += x1; x1 = rotl32(x1, 26); x1 ^= x0;
  x0 += x1; x1 = rotl32(x1, 6);  x1 ^= x0;
  x0 += k2; x1 += k0 + 5u;
  o0 = x0; o1 = x1;
}

// partitionable random_bits(32) -> uniform(0.1, 1.0), bit-matching jax _uniform
__device__ __forceinline__ float tf_uniform(u32 k0, u32 k1, u32 idx) {
  u32 o0, o1;
  threefry2x32(k0, k1, 0u, idx, o0, o1);
  u32 bits = o0 ^ o1;
  float f = __uint_as_float((bits >> 9) | 0x3F800000u) - 1.0f;  // [0,1)
  float u = __fadd_rn(__fmul_rn(f, (1.0f - 0.1f)), 0.1f);
  return fmaxf(0.1f, u);
}

__device__ __forceinline__ u64 pack_key(float u, u32 a) {
  return ((u64)__float_as_uint(u) << 32) | (u64)(u32)(~a);
}

// K1: IoU max/argmax per anchor + per-block stats (no atomics).
// m is the OUTER loop so each box is read from LDS once and reused for 4 anchors.
__global__ __launch_bounds__(1024) void k_iou(const float* __restrict__ anchors,
                                              const float* __restrict__ ann,
                                              WS* __restrict__ ws) {
  int b = blockIdx.y;
  int tid = threadIdx.x;
  int a0 = (blockIdx.x * 1024 + tid) * 4;
  __shared__ float bx1[NM], by1[NM], bx2[NM], by2[NM], barea[NM];
  __shared__ float wmax[16];
  __shared__ int wneg[16], wpos[16];
  if (tid < NM) {
    int m = tid;
    const float* p = ann + ((size_t)b * NM + m) * 5;
    float x1 = fminf(fmaxf(p[0], 0.0f), 512.0f);
    float y1 = fminf(fmaxf(p[1], 0.0f), 512.0f);
    float x2 = fminf(fmaxf(p[2], 0.0f), 512.0f);
    float y2 = fminf(fmaxf(p[3], 0.0f), 512.0f);
    bx1[m] = x1; by1[m] = y1; bx2[m] = x2; by2[m] = y2;
    barea[m] = __fmul_rn(__fsub_rn(x2, x1), __fsub_rn(y2, y1));
  }
  __syncthreads();

  const float4* a4 = (const float4*)anchors;
  float4 ap[4];
  float aarea[4], best[4];
  int bm[4];
#pragma unroll
  for (int k = 0; k < 4; k++) {
    ap[k] = a4[a0 + k];
    aarea[k] = __fmul_rn(__fsub_rn(ap[k].z, ap[k].x), __fsub_rn(ap[k].w, ap[k].y));
    best[k] = -1.0f;
    bm[k] = 0;
  }
  for (int m = 0; m < NM; m++) {
    float x1 = bx1[m], y1 = by1[m], x2 = bx2[m], y2 = by2[m], ar = barea[m];
#pragma unroll
    for (int k = 0; k < 4; k++) {
      float iw = fmaxf(__fsub_rn(fminf(ap[k].z, x2), fmaxf(ap[k].x, x1)), 0.0f);
      float ih = fmaxf(__fsub_rn(fminf(ap[k].w, y2), fmaxf(ap[k].y, y1)), 0.0f);
      float inter = __fmul_rn(iw, ih);
      float ua = fmaxf(__fsub_rn(__fadd_rn(aarea[k], ar), inter), 1e-8f);
      float iou = __fdiv_rn(inter, ua);
      if (iou > best[k]) { best[k] = iou; bm[k] = m; }
    }
  }
  u32 pack = (u32)bm[0] | ((u32)bm[1] << 8) | ((u32)bm[2] << 16) | ((u32)bm[3] << 24);
  float lmax = fmaxf(fmaxf(best[0], best[1]), fmaxf(best[2], best[3]));
  int cneg = 0, cpos = 0;
#pragma unroll
  for (int k = 0; k < 4; k++) {
    cneg += (best[k] < 0.4f && best[k] >= 0.1f) ? 1 : 0;
    cpos += (best[k] >= 0.7f) ? 1 : 0;
  }
  *(float4*)&ws->iou_max[(size_t)b * NA + a0] = make_float4(best[0], best[1], best[2], best[3]);
  ws->iou_arg4[((size_t)b * NA + a0) >> 2] = pack;

  // wave reduce then cross-wave via LDS
  for (int s = 32; s > 0; s >>= 1) {
    lmax = fmaxf(lmax, __shfl_xor(lmax, s));
    cneg += __shfl_xor(cneg, s);
    cpos += __shfl_xor(cpos, s);
  }
  int wid = tid >> 6;
  if ((tid & 63) == 0) { wmax[wid] = lmax; wneg[wid] = cneg; wpos[wid] = cpos; }
  __syncthreads();
  if (tid < 16) {
    lmax = wmax[tid]; cneg = wneg[tid]; cpos = wpos[tid];
    for (int s = 8; s > 0; s >>= 1) {
      lmax = fmaxf(lmax, __shfl_xor(lmax, s));
      cneg += __shfl_xor(cneg, s);
      cpos += __shfl_xor(cpos, s);
    }
    if (tid == 0) {
      int o = b * BLK + blockIdx.x;
      ws->blk_max[o] = lmax;
      ws->blk_nneg[o] = cneg;
      ws->blk_npos[o] = cpos;
    }
  }
}

// K2: per-image reduce of block stats; thresholds, cuts, PRNG keys, zero counters
__global__ __launch_bounds__(64) void k_stats(WS* __restrict__ ws) {
  int b = blockIdx.x, l = threadIdx.x;
  float m = (l < BLK) ? ws->blk_max[b * BLK + l] : -1.0f;
  int nn = (l < BLK) ? ws->blk_nneg[b * BLK + l] : 0;
  int np = (l < BLK) ? ws->blk_npos[b * BLK + l] : 0;
  for (int s = 32; s > 0; s >>= 1) {
    m = fmaxf(m, __shfl_xor(m, s));
    nn += __shfl_xor(nn, s);
    np += __shfl_xor(np, s);
  }
  if (l == 0) {
    ws->thresh[b] = fminf(m, 0.7f);
    int ge = (m >= 0.7f) ? 1 : 0;
    ws->ge07[b] = ge;
    ws->n_neg[b] = nn;
    ws->n_pos07[b] = np;
    ws->cut_neg[b] = (nn <= TARGET) ? -1.0f : (1.0f - 0.9f * ((float)TARGET / (float)nn));
    ws->cut_pos[b] = (ge && np > TARGET) ? (1.0f - 0.9f * ((float)TARGET / (float)np)) : -1.0f;
    ws->pos_cnt[b] = 0;
    ws->neg_cnt[b] = 0;
    u32 o0, o1;
    threefry2x32(0u, 42u, 0u, (u32)(2 * b), o0, o1);
    ws->keys[b][0] = o0; ws->keys[b][1] = o1;
    threefry2x32(0u, 42u, 0u, (u32)(2 * b + 1), o0, o1);
    ws->keys[b][2] = o0; ws->keys[b][3] = o1;
  }
}

// K3: push kept candidates with per-block LDS compaction; 1 global atomic per block per list
__global__ __launch_bounds__(1024) void k_push(WS* __restrict__ ws) {
  int b = blockIdx.y, tid = threadIdx.x;
  int a0 = (blockIdx.x * 1024 + tid) * 4;
  __shared__ u64 pbuf[BCAP], nbuf[BCAP];
  __shared__ int pcnt, ncnt, pbase, nbase;
  if (tid == 0) { pcnt = 0; ncnt = 0; }
  __syncthreads();
  float thresh = ws->thresh[b];
  float cp = ws->cut_pos[b], cn = ws->cut_neg[b];
  u32 k0 = ws->keys[b][0], k1 = ws->keys[b][1];
  u32 k2 = ws->keys[b][2], k3 = ws->keys[b][3];
  float4 im4 = *(const float4*)&ws->iou_max[(size_t)b * NA + a0];
  float imv[4] = {im4.x, im4.y, im4.z, im4.w};
#pragma unroll
  for (int k = 0; k < 4; k++) {
    float im = imv[k];
    u32 a = (u32)(a0 + k);
    if (im >= thresh) {
      float u = tf_uniform(k0, k1, a);
      if (u >= cp) {
        int p = atomicAdd(&pcnt, 1);
        if (p < BCAP) pbuf[p] = pack_key(u, a);
      }
    }
    if (im < 0.4f && im >= 0.1f) {
      float u = tf_uniform(k2, k3, a);
      if (u >= cn) {
        int p = atomicAdd(&ncnt, 1);
        if (p < BCAP) nbuf[p] = pack_key(u, a);
      }
    }
  }
  __syncthreads();
  if (tid == 0) {
    pbase = (pcnt > 0) ? atomicAdd(&ws->pos_cnt[b], pcnt) : 0;  // unclamped: exact n_pos bookkeeping
    nbase = (ncnt > 0) ? atomicAdd(&ws->neg_cnt[b], ncnt) : 0;
  }
  __syncthreads();
  int pc = min(pcnt, BCAP), nc = min(ncnt, BCAP);
  for (int i = tid; i < pc; i += 1024) { int g = pbase + i; if (g < GCAP) ws->pos_key[b * GCAP + g] = pbuf[i]; }
  for (int i = tid; i < nc; i += 1024) { int g = nbase + i; if (g < GCAP) ws->neg_key[b * GCAP + g] = nbuf[i]; }
}

// K4: rank-based top-k selection (all-pairs count) + loss terms.
// rank(i) = #{j: key_j > key_i}; keys unique => rank<r is exactly lax.top_k's set,
// and slot[rank] reproduces selection order for bit-identical summation.
__global__ __launch_bounds__(256) void k_select(const float* __restrict__ cls,
                                                const float* __restrict__ reg,
                                                const float* __restrict__ anchors,
                                                const float* __restrict__ ann,
                                                const float* __restrict__ w,
                                                WS* __restrict__ ws) {
  int b = blockIdx.x, tid = threadIdx.x;
  __shared__ u64 pk[GCAP], nk[GCAP];
  __shared__ int selp[NS], seln[2 * NS];
  __shared__ float tpos[NS], treg[NS], tneg[2 * NS];

  int mp = min(ws->pos_cnt[b], GCAP);
  int mn = min(ws->neg_cnt[b], GCAP);
  int n_pos = ws->ge07[b] ? ws->n_pos07[b] : ws->pos_cnt[b];
  int n_neg = ws->n_neg[b];
  int K = min(NS, n_pos);
  int rp = min(K, mp);
  int rn = min(min(2 * NS - K, n_neg), mn);

  int mpad = (mp + 255) & ~255;
  int npad = (mn + 255) & ~255;
  for (int i = tid; i < mpad; i += 256) pk[i] = (i < mp) ? ws->pos_key[b * GCAP + i] : 0ull;
  for (int i = tid; i < npad; i += 256) nk[i] = (i < mn) ? ws->neg_key[b * GCAP + i] : 0ull;
  if (tid < NS) { tpos[tid] = 0.0f; treg[tid] = 0.0f; }
  if (tid < 2 * NS) tneg[tid] = 0.0f;
  __syncthreads();

  // --- pos ranks (each thread owns up to GCAP/256 candidates; j-sweep shared) ---
  {
    u64 ck[GCAP / 256]; int cr[GCAP / 256];
    int nc = mpad >> 8;
#pragma unroll
    for (int c = 0; c < GCAP / 256; c++) { ck[c] = 0; cr[c] = 0; }
    for (int c = 0; c < nc; c++) ck[c] = pk[tid + (c << 8)];
    for (int j = 0; j < mp; j++) {
      u64 v = pk[j];
#pragma unroll
      for (int c = 0; c < GCAP / 256; c++) cr[c] += (v > ck[c]) ? 1 : 0;
    }
    for (int c = 0; c < nc; c++)
      if (ck[c] != 0 && cr[c] < rp) selp[cr[c]] = (int)(~(u32)ck[c]);
  }
  // --- neg ranks ---
  {
    u64 ck[GCAP / 256]; int cr[GCAP / 256];
    int nc = npad >> 8;
#pragma unroll
    for (int c = 0; c < GCAP / 256; c++) { ck[c] = 0; cr[c] = 0; }
    for (int c = 0; c < nc; c++) ck[c] = nk[tid + (c << 8)];
    for (int j = 0; j < mn; j++) {
      u64 v = nk[j];
#pragma unroll
      for (int c = 0; c < GCAP / 256; c++) cr[c] += (v > ck[c]) ? 1 : 0;
    }
    for (int c = 0; c < nc; c++)
      if (ck[c] != 0 && cr[c] < rn) seln[cr[c]] = (int)(~(u32)ck[c]);
  }
  __syncthreads();

  const float PLO = 1e-7f;
  const float PHI = (float)(1.0 - 1e-7);
  if (tid < rp) {
    int a = selp[tid];
    float p = cls[((size_t)b * NA + a) * 2 + 0];
    p = fminf(fmaxf(p, PLO), PHI);
    tpos[tid] = -logf(p);
    float4 apf = ((const float4*)anchors)[a];
    float ax1 = apf.x, ay1 = apf.y, ax2 = apf.z, ay2 = apf.w;
    float aw_ = __fsub_rn(ax2, ax1), ah_ = __fsub_rn(ay2, ay1);
    float acx = __fadd_rn(ax1, __fmul_rn(0.5f, aw_));
    float acy = __fadd_rn(ay1, __fmul_rn(0.5f, ah_));
    int m = (int)((ws->iou_arg4[((size_t)b * NA + a) >> 2] >> (8 * (a & 3))) & 0xFFu);
    const float* g = ann + ((size_t)b * NM + m) * 5;
    float gx1 = fminf(fmaxf(g[0], 0.0f), 512.0f);
    float gy1 = fminf(fmaxf(g[1], 0.0f), 512.0f);
    float gx2 = fminf(fmaxf(g[2], 0.0f), 512.0f);
    float gy2 = fminf(fmaxf(g[3], 0.0f), 512.0f);
    float gw = __fsub_rn(gx2, gx1), gh = __fsub_rn(gy2, gy1);
    float gcx = __fadd_rn(gx1, __fmul_rn(0.5f, gw));
    float gcy = __fadd_rn(gy1, __fmul_rn(0.5f, gh));
    gw = fmaxf(gw, 1.0f); gh = fmaxf(gh, 1.0f);
    float t0 = __fdiv_rn(__fdiv_rn(__fsub_rn(gcx, acx), aw_), 0.1f);
    float t1 = __fdiv_rn(__fdiv_rn(__fsub_rn(gcy, acy), ah_), 0.1f);
    float t2 = __fdiv_rn(logf(__fdiv_rn(gw, aw_)), 0.2f);
    float t3 = __fdiv_rn(logf(__fdiv_rn(gh, ah_)), 0.2f);
    const float* rg = reg + ((size_t)b * NA + a) * 4;
    float tt[4] = {t0, t1, t2, t3};
    float s = 0.0f;
#pragma unroll
    for (int c = 0; c < 4; c++) {
      float d = fabsf(__fsub_rn(tt[c], rg[c]));
      float q = (d <= (float)(1.0 / 9.0)) ? __fmul_rn(__fmul_rn(4.5f, d), d)
                                          : __fsub_rn(d, (float)(0.5 / 9.0));
      s = __fadd_rn(s, q);
    }
    treg[tid] = s;
  }
  if (tid < rn) {
    int a = seln[tid];
    bool ispos = false;
    for (int i = 0; i < rp; i++) if (selp[i] == a) ispos = true;
    if (!ispos) {
      float p = cls[((size_t)b * NA + a) * 2 + 1];
      p = fminf(fmaxf(p, PLO), PHI);
      tneg[tid] = -logf(p);
    }
  }
  __syncthreads();
  if (tid == 0) {
    float cs = 0.0f;
    for (int i = 0; i < NS; i++) cs = __fadd_rn(cs, tpos[i]);
    for (int i = 0; i < 2 * NS; i++) cs = __fadd_rn(cs, tneg[i]);
    float rs = 0.0f;
    for (int i = 0; i < NS; i++) rs = __fadd_rn(rs, treg[i]);
    ws->cls_img[b] = __fdiv_rn(cs, 64.0f);
    ws->reg_img[b] = __fdiv_rn(__fmul_rn(rs, w[b * 4 + 0]), 64.0f);
  }
}

__global__ __launch_bounds__(64) void k_final(WS* __restrict__ ws, float* __restrict__ out) {
  if (threadIdx.x == 0) {
    float c = 0.0f, r = 0.0f;
    for (int b = 0; b < NB; b++) {
      c = __fadd_rn(c, ws->cls_img[b]);
      r = __fadd_rn(r, ws->reg_img[b]);
    }
    out[0] = __fdiv_rn(c, 16.0f);
    out[1] = __fdiv_rn(r, 16.0f);
  }
}

extern "C" void kernel_launch(void* const* d_in, const int* in_sizes, int n_in,
                              void* d_out, int out_size, void* d_ws, size_t ws_size,
                              hipStream_t stream) {
  const float* cls = (const float*)d_in[0];
  const float* reg = (const float*)d_in[1];
  const float* anchors = (const float*)d_in[2];  // (1, A, 4)
  const float* ann = (const float*)d_in[3];      // (B, M, 5)
  const float* w = (const float*)d_in[4];        // (B, 4)
  float* out = (float*)d_out;
  if (ws_size < sizeof(WS)) return;
  WS* ws = (WS*)d_ws;

  hipLaunchKernelGGL(k_iou, dim3(BLK, NB), dim3(1024), 0, stream, anchors, ann, ws);
  hipLaunchKernelGGL(k_stats, dim3(NB), dim3(64), 0, stream, ws);
  hipLaunchKernelGGL(k_push, dim3(BLK, NB), dim3(1024), 0, stream, ws);
  hipLaunchKernelGGL(k_select, dim3(NB), dim3(256), 0, stream, cls, reg, anchors, ann, w, ws);
  hipLaunchKernelGGL(k_final, dim3(1), dim3(64), 0, stream, ws, out);
}

// Round 4
// 79.262 us; speedup vs baseline: 7.6554x; 1.0260x over previous
//
#include <hip/hip_runtime.h>

#define NB 16
#define NA 98304
#define NM 32
#define NS 32
#define BLKI 96         // blocks per image: 256 thr x 4 anchors = 1024
#define TARGET 256      // expected kept candidates per list (superset of top-64, ~12 sigma margin)
#define GCAP 1024       // global candidate capacity per image per list
#define BCAP 512        // per-block LDS compaction capacity

typedef unsigned int u32;
typedef unsigned long long u64;

static_assert(NA == BLKI * 256 * 4, "coverage");

struct WS {
  u64   pos_key[NB * GCAP];
  u64   neg_key[NB * GCAP];
  float iou_max[NB * NA];
  u32   iou_arg4[NB * NA / 4];     // 4 x u8 packed
  float blk_max[NB * BLKI];
  int   blk_nneg[NB * BLKI];
  int   blk_npos[NB * BLKI];
  float thresh[NB], cut_pos[NB], cut_neg[NB];
  int   n_neg[NB], n_pos07[NB], ge07[NB];
  u32   keys[NB][4];
  int   pos_cnt[NB], neg_cnt[NB];
  float cls_img[NB], reg_img[NB];
};

__device__ __forceinline__ u32 rotl32(u32 v, int d) { return (v << d) | (v >> (32 - d)); }

// Threefry-2x32, 20 rounds, exactly as jax/_src/prng.py
__device__ __forceinline__ void threefry2x32(u32 k0, u32 k1, u32 x0, u32 x1, u32& o0, u32& o1) {
  u32 k2 = k0 ^ k1 ^ 0x1BD11BDAu;
  x0 += k0; x1 += k1;
  x0 += x1; x1 = rotl32(x1, 13); x1 ^= x0;
  x0 += x1; x1 = rotl32(x1, 15); x1 ^= x0;
  x0 += x1; x1 = rotl32(x1, 26); x1 ^= x0;
  x0 += x1; x1 = rotl32(x1, 6);  x1 ^= x0;
  x0 += k1; x1 += k2 + 1u;
  x0 += x1; x1 = rotl32(x1, 17); x1 ^= x0;
  x0 += x1; x1 = rotl32(x1, 29); x1 ^= x0;
  x0 += x1; x1 = rotl32(x1, 16); x1 ^= x0;
  x0 += x1; x1 = rotl32(x1, 24); x1 ^= x0;
  x0 += k2; x1 += k0 + 2u;
  x0 += x1; x1 = rotl32(x1, 13); x1 ^= x0;
  x0 += x1; x1 = rotl32(x1, 15); x1 ^= x0;
  x0 += x1; x1 = rotl32(x1, 26); x1 ^= x0;
  x0 += x1; x1 = rotl32(x1, 6);  x1 ^= x0;
  x0 += k0; x1 += k1 + 3u;
  x0 += x1; x1 = rotl32(x1, 17); x1 ^= x0;
  x0 += x1; x1 = rotl32(x1, 29); x1 ^= x0;
  x0 += x1; x1 = rotl32(x1, 16); x1 ^= x0;
  x0 += x1; x1 = rotl32(x1, 24); x1 ^= x0;
  x0 += k1; x1 += k2 + 4u;
  x0 += x1; x1 = rotl32(x1, 13); x1 ^= x0;
  x0 += x1; x1 = rotl32(x1, 15); x1 ^= x0;
  x0 += x1; x1 = rotl32(x1, 26); x1 ^= x0;
  x0 += x1; x1 = rotl32(x1, 6);  x1 ^= x0;
  x0 += k2; x1 += k0 + 5u;
  o0 = x0; o1 = x1;
}

// partitionable random_bits(32) -> uniform(0.1, 1.0), bit-matching jax _uniform
__device__ __forceinline__ float tf_uniform(u32 k0, u32 k1, u32 idx) {
  u32 o0, o1;
  threefry2x32(k0, k1, 0u, idx, o0, o1);
  u32 bits = o0 ^ o1;
  float f = __uint_as_float((bits >> 9) | 0x3F800000u) - 1.0f;  // [0,1)
  float u = __fadd_rn(__fmul_rn(f, (1.0f - 0.1f)), 0.1f);
  return fmaxf(0.1f, u);
}

__device__ __forceinline__ u64 pack_key(float u, u32 a) {
  return ((u64)__float_as_uint(u) << 32) | (u64)(u32)(~a);
}

// K1: IoU max/argmax per anchor + per-block stats (no atomics).
// Argmax via exact cross-multiplication (inter_a*ua_b > inter_b*ua_a); ONE
// division per anchor at the end. Rounding monotonicity => stored max value is
// bit-identical to max of per-pair rounded quotients.
__global__ __launch_bounds__(256) void k_iou(const float* __restrict__ anchors,
                                             const float* __restrict__ ann,
                                             WS* __restrict__ ws) {
  int b = blockIdx.y;
  int tid = threadIdx.x;
  int a0 = (blockIdx.x * 256 + tid) * 4;
  __shared__ float bx1[NM], by1[NM], bx2[NM], by2[NM], barea[NM];
  __shared__ float wmax[4];
  __shared__ int wneg[4], wpos[4];
  if (tid < NM) {
    int m = tid;
    const float* p = ann + ((size_t)b * NM + m) * 5;
    float x1 = fminf(fmaxf(p[0], 0.0f), 512.0f);
    float y1 = fminf(fmaxf(p[1], 0.0f), 512.0f);
    float x2 = fminf(fmaxf(p[2], 0.0f), 512.0f);
    float y2 = fminf(fmaxf(p[3], 0.0f), 512.0f);
    bx1[m] = x1; by1[m] = y1; bx2[m] = x2; by2[m] = y2;
    barea[m] = __fmul_rn(__fsub_rn(x2, x1), __fsub_rn(y2, y1));
  }
  __syncthreads();

  const float4* a4 = (const float4*)anchors;
  float4 ap[4];
  float aarea[4], bi[4], bu[4];
  int bm[4];
#pragma unroll
  for (int k = 0; k < 4; k++) {
    ap[k] = a4[a0 + k];
    aarea[k] = __fmul_rn(__fsub_rn(ap[k].z, ap[k].x), __fsub_rn(ap[k].w, ap[k].y));
    bi[k] = -1.0f;   // best_inter: start at q = -1/1 so m=0 always wins first
    bu[k] = 1.0f;    // best_ua
    bm[k] = 0;
  }
#pragma unroll 2
  for (int m = 0; m < NM; m++) {
    float x1 = bx1[m], y1 = by1[m], x2 = bx2[m], y2 = by2[m], ar = barea[m];
#pragma unroll
    for (int k = 0; k < 4; k++) {
      float iw = fmaxf(__fsub_rn(fminf(ap[k].z, x2), fmaxf(ap[k].x, x1)), 0.0f);
      float ih = fmaxf(__fsub_rn(fminf(ap[k].w, y2), fmaxf(ap[k].y, y1)), 0.0f);
      float inter = __fmul_rn(iw, ih);
      float ua = fmaxf(__fsub_rn(__fadd_rn(aarea[k], ar), inter), 1e-8f);
      // inter/ua > bi/bu  <=>  inter*bu > bi*ua   (all >=0 except initial bi=-1)
      bool upd = __fmul_rn(inter, bu[k]) > __fmul_rn(bi[k], ua);
      bi[k] = upd ? inter : bi[k];
      bu[k] = upd ? ua : bu[k];
      bm[k] = upd ? m : bm[k];
    }
  }
  float best[4];
#pragma unroll
  for (int k = 0; k < 4; k++) best[k] = __fdiv_rn(bi[k], bu[k]);

  u32 pack = (u32)bm[0] | ((u32)bm[1] << 8) | ((u32)bm[2] << 16) | ((u32)bm[3] << 24);
  float lmax = fmaxf(fmaxf(best[0], best[1]), fmaxf(best[2], best[3]));
  int cneg = 0, cpos = 0;
#pragma unroll
  for (int k = 0; k < 4; k++) {
    cneg += (best[k] < 0.4f && best[k] >= 0.1f) ? 1 : 0;
    cpos += (best[k] >= 0.7f) ? 1 : 0;
  }
  *(float4*)&ws->iou_max[(size_t)b * NA + a0] = make_float4(best[0], best[1], best[2], best[3]);
  ws->iou_arg4[((size_t)b * NA + a0) >> 2] = pack;

  // wave reduce then cross-wave via LDS
  for (int s = 32; s > 0; s >>= 1) {
    lmax = fmaxf(lmax, __shfl_xor(lmax, s));
    cneg += __shfl_xor(cneg, s);
    cpos += __shfl_xor(cpos, s);
  }
  int wid = tid >> 6;
  if ((tid & 63) == 0) { wmax[wid] = lmax; wneg[wid] = cneg; wpos[wid] = cpos; }
  __syncthreads();
  if (tid < 4) {
    lmax = wmax[tid]; cneg = wneg[tid]; cpos = wpos[tid];
    for (int s = 2; s > 0; s >>= 1) {
      lmax = fmaxf(lmax, __shfl_xor(lmax, s));
      cneg += __shfl_xor(cneg, s);
      cpos += __shfl_xor(cpos, s);
    }
    if (tid == 0) {
      int o = b * BLKI + blockIdx.x;
      ws->blk_max[o] = lmax;
      ws->blk_nneg[o] = cneg;
      ws->blk_npos[o] = cpos;
    }
  }
}

// K2: per-image reduce of block stats; thresholds, cuts, PRNG keys, zero counters
__global__ __launch_bounds__(128) void k_stats(WS* __restrict__ ws) {
  int b = blockIdx.x, l = threadIdx.x;
  __shared__ float sm[2];
  __shared__ int sn[2], sp[2];
  float m = -1.0f;
  int nn = 0, np = 0;
  for (int i = l; i < BLKI; i += 128) {
    m = fmaxf(m, ws->blk_max[b * BLKI + i]);
    nn += ws->blk_nneg[b * BLKI + i];
    np += ws->blk_npos[b * BLKI + i];
  }
  for (int s = 32; s > 0; s >>= 1) {
    m = fmaxf(m, __shfl_xor(m, s));
    nn += __shfl_xor(nn, s);
    np += __shfl_xor(np, s);
  }
  int wid = l >> 6;
  if ((l & 63) == 0) { sm[wid] = m; sn[wid] = nn; sp[wid] = np; }
  __syncthreads();
  if (l == 0) {
    m = fmaxf(sm[0], sm[1]); nn = sn[0] + sn[1]; np = sp[0] + sp[1];
    ws->thresh[b] = fminf(m, 0.7f);
    int ge = (m >= 0.7f) ? 1 : 0;
    ws->ge07[b] = ge;
    ws->n_neg[b] = nn;
    ws->n_pos07[b] = np;
    ws->cut_neg[b] = (nn <= TARGET) ? -1.0f : (1.0f - 0.9f * ((float)TARGET / (float)nn));
    ws->cut_pos[b] = (ge && np > TARGET) ? (1.0f - 0.9f * ((float)TARGET / (float)np)) : -1.0f;
    ws->pos_cnt[b] = 0;
    ws->neg_cnt[b] = 0;
    u32 o0, o1;
    threefry2x32(0u, 42u, 0u, (u32)(2 * b), o0, o1);
    ws->keys[b][0] = o0; ws->keys[b][1] = o1;
    threefry2x32(0u, 42u, 0u, (u32)(2 * b + 1), o0, o1);
    ws->keys[b][2] = o0; ws->keys[b][3] = o1;
  }
}

// K3: push kept candidates with per-block LDS compaction; 1 global atomic per block per list
__global__ __launch_bounds__(256) void k_push(WS* __restrict__ ws) {
  int b = blockIdx.y, tid = threadIdx.x;
  int a0 = (blockIdx.x * 256 + tid) * 4;
  __shared__ u64 pbuf[BCAP], nbuf[BCAP];
  __shared__ int pcnt, ncnt, pbase, nbase;
  if (tid == 0) { pcnt = 0; ncnt = 0; }
  __syncthreads();
  float thresh = ws->thresh[b];
  float cp = ws->cut_pos[b], cn = ws->cut_neg[b];
  u32 k0 = ws->keys[b][0], k1 = ws->keys[b][1];
  u32 k2 = ws->keys[b][2], k3 = ws->keys[b][3];
  float4 im4 = *(const float4*)&ws->iou_max[(size_t)b * NA + a0];
  float imv[4] = {im4.x, im4.y, im4.z, im4.w};
#pragma unroll
  for (int k = 0; k < 4; k++) {
    float im = imv[k];
    u32 a = (u32)(a0 + k);
    if (im >= thresh) {
      float u = tf_uniform(k0, k1, a);
      if (u >= cp) {
        int p = atomicAdd(&pcnt, 1);
        if (p < BCAP) pbuf[p] = pack_key(u, a);
      }
    }
    if (im < 0.4f && im >= 0.1f) {
      float u = tf_uniform(k2, k3, a);
      if (u >= cn) {
        int p = atomicAdd(&ncnt, 1);
        if (p < BCAP) nbuf[p] = pack_key(u, a);
      }
    }
  }
  __syncthreads();
  if (tid == 0) {
    pbase = (pcnt > 0) ? atomicAdd(&ws->pos_cnt[b], pcnt) : 0;  // unclamped: exact n_pos bookkeeping
    nbase = (ncnt > 0) ? atomicAdd(&ws->neg_cnt[b], ncnt) : 0;
  }
  __syncthreads();
  int pc = min(pcnt, BCAP), nc = min(ncnt, BCAP);
  for (int i = tid; i < pc; i += 256) { int g = pbase + i; if (g < GCAP) ws->pos_key[b * GCAP + g] = pbuf[i]; }
  for (int i = tid; i < nc; i += 256) { int g = nbase + i; if (g < GCAP) ws->neg_key[b * GCAP + g] = nbuf[i]; }
}

// K4: rank-based top-k selection (all-pairs count) + loss terms.
// rank(i) = #{j: key_j > key_i}; keys unique => rank<r is exactly lax.top_k's set,
// and slot[rank] reproduces selection order for bit-identical summation.
__global__ __launch_bounds__(256) void k_select(const float* __restrict__ cls,
                                                const float* __restrict__ reg,
                                                const float* __restrict__ anchors,
                                                const float* __restrict__ ann,
                                                const float* __restrict__ w,
                                                WS* __restrict__ ws) {
  int b = blockIdx.x, tid = threadIdx.x;
  __shared__ u64 pk[GCAP], nk[GCAP];
  __shared__ int selp[NS], seln[2 * NS];
  __shared__ float tpos[NS], treg[NS], tneg[2 * NS];

  int mp = min(ws->pos_cnt[b], GCAP);
  int mn = min(ws->neg_cnt[b], GCAP);
  int n_pos = ws->ge07[b] ? ws->n_pos07[b] : ws->pos_cnt[b];
  int n_neg = ws->n_neg[b];
  int K = min(NS, n_pos);
  int rp = min(K, mp);
  int rn = min(min(2 * NS - K, n_neg), mn);

  int mpad = (mp + 255) & ~255;
  int npad = (mn + 255) & ~255;
  for (int i = tid; i < mpad; i += 256) pk[i] = (i < mp) ? ws->pos_key[b * GCAP + i] : 0ull;
  for (int i = tid; i < npad; i += 256) nk[i] = (i < mn) ? ws->neg_key[b * GCAP + i] : 0ull;
  if (tid < NS) { tpos[tid] = 0.0f; treg[tid] = 0.0f; }
  if (tid < 2 * NS) tneg[tid] = 0.0f;
  __syncthreads();

  // --- pos ranks (each thread owns up to GCAP/256 candidates; j-sweep shared) ---
  {
    u64 ck[GCAP / 256]; int cr[GCAP / 256];
    int nc = mpad >> 8;
#pragma unroll
    for (int c = 0; c < GCAP / 256; c++) { ck[c] = 0; cr[c] = 0; }
    for (int c = 0; c < nc; c++) ck[c] = pk[tid + (c << 8)];
    for (int j = 0; j < mp; j++) {
      u64 v = pk[j];
#pragma unroll
      for (int c = 0; c < GCAP / 256; c++) cr[c] += (v > ck[c]) ? 1 : 0;
    }
    for (int c = 0; c < nc; c++)
      if (ck[c] != 0 && cr[c] < rp) selp[cr[c]] = (int)(~(u32)ck[c]);
  }
  // --- neg ranks ---
  {
    u64 ck[GCAP / 256]; int cr[GCAP / 256];
    int nc = npad >> 8;
#pragma unroll
    for (int c = 0; c < GCAP / 256; c++) { ck[c] = 0; cr[c] = 0; }
    for (int c = 0; c < nc; c++) ck[c] = nk[tid + (c << 8)];
    for (int j = 0; j < mn; j++) {
      u64 v = nk[j];
#pragma unroll
      for (int c = 0; c < GCAP / 256; c++) cr[c] += (v > ck[c]) ? 1 : 0;
    }
    for (int c = 0; c < nc; c++)
      if (ck[c] != 0 && cr[c] < rn) seln[cr[c]] = (int)(~(u32)ck[c]);
  }
  __syncthreads();

  const float PLO = 1e-7f;
  const float PHI = (float)(1.0 - 1e-7);
  if (tid < rp) {
    int a = selp[tid];
    float p = cls[((size_t)b * NA + a) * 2 + 0];
    p = fminf(fmaxf(p, PLO), PHI);
    tpos[tid] = -logf(p);
    float4 apf = ((const float4*)anchors)[a];
    float ax1 = apf.x, ay1 = apf.y, ax2 = apf.z, ay2 = apf.w;
    float aw_ = __fsub_rn(ax2, ax1), ah_ = __fsub_rn(ay2, ay1);
    float acx = __fadd_rn(ax1, __fmul_rn(0.5f, aw_));
    float acy = __fadd_rn(ay1, __fmul_rn(0.5f, ah_));
    int m = (int)((ws->iou_arg4[((size_t)b * NA + a) >> 2] >> (8 * (a & 3))) & 0xFFu);
    const float* g = ann + ((size_t)b * NM + m) * 5;
    float gx1 = fminf(fmaxf(g[0], 0.0f), 512.0f);
    float gy1 = fminf(fmaxf(g[1], 0.0f), 512.0f);
    float gx2 = fminf(fmaxf(g[2], 0.0f), 512.0f);
    float gy2 = fminf(fmaxf(g[3], 0.0f), 512.0f);
    float gw = __fsub_rn(gx2, gx1), gh = __fsub_rn(gy2, gy1);
    float gcx = __fadd_rn(gx1, __fmul_rn(0.5f, gw));
    float gcy = __fadd_rn(gy1, __fmul_rn(0.5f, gh));
    gw = fmaxf(gw, 1.0f); gh = fmaxf(gh, 1.0f);
    float t0 = __fdiv_rn(__fdiv_rn(__fsub_rn(gcx, acx), aw_), 0.1f);
    float t1 = __fdiv_rn(__fdiv_rn(__fsub_rn(gcy, acy), ah_), 0.1f);
    float t2 = __fdiv_rn(logf(__fdiv_rn(gw, aw_)), 0.2f);
    float t3 = __fdiv_rn(logf(__fdiv_rn(gh, ah_)), 0.2f);
    const float* rg = reg + ((size_t)b * NA + a) * 4;
    float tt[4] = {t0, t1, t2, t3};
    float s = 0.0f;
#pragma unroll
    for (int c = 0; c < 4; c++) {
      float d = fabsf(__fsub_rn(tt[c], rg[c]));
      float q = (d <= (float)(1.0 / 9.0)) ? __fmul_rn(__fmul_rn(4.5f, d), d)
                                          : __fsub_rn(d, (float)(0.5 / 9.0));
      s = __fadd_rn(s, q);
    }
    treg[tid] = s;
  }
  if (tid < rn) {
    int a = seln[tid];
    bool ispos = false;
    for (int i = 0; i < rp; i++) if (selp[i] == a) ispos = true;
    if (!ispos) {
      float p = cls[((size_t)b * NA + a) * 2 + 1];
      p = fminf(fmaxf(p, PLO), PHI);
      tneg[tid] = -logf(p);
    }
  }
  __syncthreads();
  if (tid == 0) {
    float cs = 0.0f;
    for (int i = 0; i < NS; i++) cs = __fadd_rn(cs, tpos[i]);
    for (int i = 0; i < 2 * NS; i++) cs = __fadd_rn(cs, tneg[i]);
    float rs = 0.0f;
    for (int i = 0; i < NS; i++) rs = __fadd_rn(rs, treg[i]);
    ws->cls_img[b] = __fdiv_rn(cs, 64.0f);
    ws->reg_img[b] = __fdiv_rn(__fmul_rn(rs, w[b * 4 + 0]), 64.0f);
  }
}

__global__ __launch_bounds__(64) void k_final(WS* __restrict__ ws, float* __restrict__ out) {
  if (threadIdx.x == 0) {
    float c = 0.0f, r = 0.0f;
    for (int b = 0; b < NB; b++) {
      c = __fadd_rn(c, ws->cls_img[b]);
      r = __fadd_rn(r, ws->reg_img[b]);
    }
    out[0] = __fdiv_rn(c, 16.0f);
    out[1] = __fdiv_rn(r, 16.0f);
  }
}

extern "C" void kernel_launch(void* const* d_in, const int* in_sizes, int n_in,
                              void* d_out, int out_size, void* d_ws, size_t ws_size,
                              hipStream_t stream) {
  const float* cls = (const float*)d_in[0];
  const float* reg = (const float*)d_in[1];
  const float* anchors = (const float*)d_in[2];  // (1, A, 4)
  const float* ann = (const float*)d_in[3];      // (B, M, 5)
  const float* w = (const float*)d_in[4];        // (B, 4)
  float* out = (float*)d_out;
  if (ws_size < sizeof(WS)) return;
  WS* ws = (WS*)d_ws;

  hipLaunchKernelGGL(k_iou, dim3(BLKI, NB), dim3(256), 0, stream, anchors, ann, ws);
  hipLaunchKernelGGL(k_stats, dim3(NB), dim3(128), 0, stream, ws);
  hipLaunchKernelGGL(k_push, dim3(BLKI, NB), dim3(256), 0, stream, ws);
  hipLaunchKernelGGL(k_select, dim3(NB), dim3(256), 0, stream, cls, reg, anchors, ann, w, ws);
  hipLaunchKernelGGL(k_final, dim3(1), dim3(64), 0, stream, ws, out);
}